// Round 7
// baseline (638.427 us; speedup 1.0000x reference)
//
#include <hip/hip_runtime.h>

#define SEQ   2048
#define DIM   4096
#define NH    32
#define NKV   8
#define HD    128
#define KVDIM 1024   // NKV*HD

typedef __attribute__((ext_vector_type(8))) short bf16x8;
typedef __attribute__((ext_vector_type(4))) float f32x4;

static __device__ __forceinline__ unsigned short f2bf(float x) {
    unsigned int u = __float_as_uint(x);
    unsigned int r = (u + 0x7fffu + ((u >> 16) & 1u)) >> 16;   // RNE
    return (unsigned short)r;
}

// ---------------------------------------------------------------------------
// Fused fp32 -> bf16 convert of x|wq|wk|wv|wo into the contiguous ws region
// [xb][wq][wk][wv][wo]. One launch, grid-stride, float4/ushort4.
// ---------------------------------------------------------------------------
#define N_X4   2097152   // 2048*4096/4
#define B0_4   2097152
#define B1_4   6291456   // +4096*4096/4
#define B2_4   7340032   // +1024*4096/4
#define B3_4   8388608   // +1024*4096/4
#define TOT4  12582912   // +4096*4096/4

__global__ __launch_bounds__(256) void cvt5_kernel(const float* __restrict__ x,
                                                   const float* __restrict__ wq,
                                                   const float* __restrict__ wk,
                                                   const float* __restrict__ wv,
                                                   const float* __restrict__ wo,
                                                   unsigned short* __restrict__ d)
{
    int i = blockIdx.x * 256 + threadIdx.x;
    const int stride = gridDim.x * 256;
    for (; i < TOT4; i += stride) {
        const float* s; int off;
        if      (i < B0_4) { s = x;  off = i;         }
        else if (i < B1_4) { s = wq; off = i - B0_4;  }
        else if (i < B2_4) { s = wk; off = i - B1_4;  }
        else if (i < B3_4) { s = wv; off = i - B2_4;  }
        else               { s = wo; off = i - B3_4;  }
        float4 v = reinterpret_cast<const float4*>(s)[off];
        ushort4 u;
        u.x = f2bf(v.x); u.y = f2bf(v.y); u.z = f2bf(v.z); u.w = f2bf(v.w);
        reinterpret_cast<ushort4*>(d)[i] = u;
    }
}

// fp32 -> bf16 bulk convert (fallback path only)
__global__ __launch_bounds__(256) void cvt_kernel(const float* __restrict__ s,
                                                  unsigned short* __restrict__ d, int n4)
{
    int i = blockIdx.x * 256 + threadIdx.x;
    int stride = gridDim.x * 256;
    for (; i < n4; i += stride) {
        float4 v = reinterpret_cast<const float4*>(s)[i];
        ushort4 u;
        u.x = f2bf(v.x); u.y = f2bf(v.y); u.z = f2bf(v.z); u.w = f2bf(v.w);
        reinterpret_cast<ushort4*>(d)[i] = u;
    }
}

// ---------------------------------------------------------------------------
// GEMM: C[M,N] = A[M,4096] . W[N,4096]^T
// 128x128 tile, BK=32, 4 waves (2x2), wave 64x64 = 4x4 MFMA 16x16x32.
// bf16 operands (ABF&&WBF): double-buffered LDS + global_load_lds prefetch,
//   ONE barrier per K-step (2-phase pipeline), XCD-aware block swizzle.
// fp32 operand: reg-staged convert into padded LDS (2-barrier, fallback).
// MODE: 1 = bf16 out + fused RoPE      2 = bf16 out transposed
//       3 = fp32 out                   5 = fused QKV: n0<4096 Q-RoPE->Cp,
//           n0<5120 K-RoPE->Cp2 (ld 1024), else V-transpose->Cp3
// ---------------------------------------------------------------------------
template<bool ABF, bool WBF, int MODE>
__global__ __launch_bounds__(256) void gemm_bt(
    const void* __restrict__ Ap, const void* __restrict__ Wp,
    void* __restrict__ Cp, void* __restrict__ Cp2, void* __restrict__ Cp3, int ldC,
    const float* __restrict__ cosT, const float* __restrict__ sinT)
{
    constexpr bool DB = ABF && WBF;
    constexpr int AS = ABF ? 32 : 40;
    constexpr int BS = WBF ? 32 : 40;
    __shared__ unsigned short As[DB ? 2 : 1][128 * AS];
    __shared__ unsigned short Bs[DB ? 2 : 1][128 * BS];

    const int t  = threadIdx.x;
    const int w  = t >> 6, l = t & 63;
    const int lr = l & 15, lg = l >> 4;
    const int wm = (w >> 1) * 64, wn = (w & 1) * 64;

    // XCD-aware bijective block swizzle (nwg % 8 == 0 for all our grids)
    const int gx  = gridDim.x;
    const int nwg = gx * gridDim.y;
    int flat = blockIdx.y * gx + blockIdx.x;
    if ((nwg & 7) == 0) flat = (flat & 7) * (nwg >> 3) + (flat >> 3);
    const int m0 = (flat / gx) * 128, n0 = (flat % gx) * 128;

    f32x4 acc[4][4] = {};

    if constexpr (DB) {
        const unsigned short* A = (const unsigned short*)Ap;
        const unsigned short* B = (const unsigned short*)Wp;

        auto STAGE = [&](int k0, int b) {
            #pragma unroll
            for (int i = 0; i < 2; ++i) {
                const unsigned short* src =
                    A + (size_t)(m0 + i * 64 + w * 16 + (l >> 2)) * 4096 + k0 + (l & 3) * 8;
                __builtin_amdgcn_global_load_lds(
                    (const __attribute__((address_space(1))) void*)src,
                    (__attribute__((address_space(3))) void*)&As[b][(i * 64 + w * 16) * 32],
                    16, 0, 0);
            }
            #pragma unroll
            for (int i = 0; i < 2; ++i) {
                const unsigned short* src =
                    B + (size_t)(n0 + i * 64 + w * 16 + (l >> 2)) * 4096 + k0 + (l & 3) * 8;
                __builtin_amdgcn_global_load_lds(
                    (const __attribute__((address_space(1))) void*)src,
                    (__attribute__((address_space(3))) void*)&Bs[b][(i * 64 + w * 16) * 32],
                    16, 0, 0);
            }
        };

        STAGE(0, 0);
        __syncthreads();
        int cur = 0;
        for (int k0 = 0; k0 < 4096; k0 += 32) {
            if (k0 + 32 < 4096) STAGE(k0 + 32, cur ^ 1);

            bf16x8 af[4], bfr[4];
            #pragma unroll
            for (int m = 0; m < 4; ++m)
                af[m] = *reinterpret_cast<const bf16x8*>(&As[cur][(wm + m * 16 + lr) * 32 + lg * 8]);
            #pragma unroll
            for (int n = 0; n < 4; ++n)
                bfr[n] = *reinterpret_cast<const bf16x8*>(&Bs[cur][(wn + n * 16 + lr) * 32 + lg * 8]);
            #pragma unroll
            for (int m = 0; m < 4; ++m)
                #pragma unroll
                for (int n = 0; n < 4; ++n)
                    acc[m][n] = __builtin_amdgcn_mfma_f32_16x16x32_bf16(af[m], bfr[n], acc[m][n], 0, 0, 0);
            __syncthreads();   // waves done with buf[cur]; buf[cur^1] loads drained
            cur ^= 1;
        }
    } else {
        for (int k0 = 0; k0 < 4096; k0 += 32) {
            {
                const float* A = (const float*)Ap;
                #pragma unroll
                for (int i = 0; i < 4; ++i) {
                    int row = (t >> 3) + 32 * i, kc = (t & 7) * 4;
                    float4 v = *reinterpret_cast<const float4*>(A + (size_t)(m0 + row) * 4096 + k0 + kc);
                    ushort4 u;
                    u.x = f2bf(v.x); u.y = f2bf(v.y); u.z = f2bf(v.z); u.w = f2bf(v.w);
                    *reinterpret_cast<ushort4*>(&As[0][row * 40 + kc]) = u;
                }
            }
            {
                const float* B = (const float*)Wp;
                #pragma unroll
                for (int i = 0; i < 4; ++i) {
                    int row = (t >> 3) + 32 * i, kc = (t & 7) * 4;
                    float4 v = *reinterpret_cast<const float4*>(B + (size_t)(n0 + row) * 4096 + k0 + kc);
                    ushort4 u;
                    u.x = f2bf(v.x); u.y = f2bf(v.y); u.z = f2bf(v.z); u.w = f2bf(v.w);
                    *reinterpret_cast<ushort4*>(&Bs[0][row * 40 + kc]) = u;
                }
            }
            __syncthreads();

            bf16x8 af[4], bfr[4];
            #pragma unroll
            for (int m = 0; m < 4; ++m)
                af[m] = *reinterpret_cast<const bf16x8*>(&As[0][(wm + m * 16 + lr) * AS + lg * 8]);
            #pragma unroll
            for (int n = 0; n < 4; ++n)
                bfr[n] = *reinterpret_cast<const bf16x8*>(&Bs[0][(wn + n * 16 + lr) * BS + lg * 8]);
            #pragma unroll
            for (int m = 0; m < 4; ++m)
                #pragma unroll
                for (int n = 0; n < 4; ++n)
                    acc[m][n] = __builtin_amdgcn_mfma_f32_16x16x32_bf16(af[m], bfr[n], acc[m][n], 0, 0, 0);
            __syncthreads();
        }
    }

    // ---- epilogues ----
    if constexpr (MODE == 3) {
        float* C = (float*)Cp;
        #pragma unroll
        for (int m = 0; m < 4; ++m)
            #pragma unroll
            for (int n = 0; n < 4; ++n)
                #pragma unroll
                for (int j = 0; j < 4; ++j)
                    C[(size_t)(m0 + wm + m * 16 + lg * 4 + j) * ldC + n0 + wn + n * 16 + lr] =
                        acc[m][n][j];
    } else if constexpr (MODE == 2) {
        unsigned short* VT = (unsigned short*)Cp;
        #pragma unroll
        for (int m = 0; m < 4; ++m)
            #pragma unroll
            for (int n = 0; n < 4; ++n) {
                int col = n0 + wn + n * 16 + lr;
                int r0  = m0 + wm + m * 16 + lg * 4;
                ushort4 u;
                u.x = f2bf(acc[m][n][0]); u.y = f2bf(acc[m][n][1]);
                u.z = f2bf(acc[m][n][2]); u.w = f2bf(acc[m][n][3]);
                *reinterpret_cast<ushort4*>(&VT[(size_t)col * SEQ + r0]) = u;
            }
    } else if constexpr (MODE == 1) {
        unsigned short* C = (unsigned short*)Cp;
        #pragma unroll
        for (int m = 0; m < 4; ++m)
            #pragma unroll
            for (int n = 0; n < 4; ++n) {
                int col = n0 + wn + n * 16 + lr;
                int p   = (col & 127) >> 1;
                float sg = (col & 1) ? 1.f : -1.f;
                #pragma unroll
                for (int j = 0; j < 4; ++j) {
                    int row = m0 + wm + m * 16 + lg * 4 + j;
                    float v  = acc[m][n][j];
                    float pr = __shfl_xor(v, 1);
                    float o  = v * cosT[row * 64 + p] + sg * sinT[row * 64 + p] * pr;
                    C[(size_t)row * ldC + col] = f2bf(o);
                }
            }
    } else {  // MODE 5: fused QKV
        if (n0 < 5120) {
            unsigned short* C;
            int ldc2, csub;
            if (n0 < 4096) { C = (unsigned short*)Cp;  ldc2 = DIM;   csub = 0;    }
            else           { C = (unsigned short*)Cp2; ldc2 = KVDIM; csub = 4096; }
            #pragma unroll
            for (int m = 0; m < 4; ++m)
                #pragma unroll
                for (int n = 0; n < 4; ++n) {
                    int col = n0 + wn + n * 16 + lr - csub;
                    int p   = (col & 127) >> 1;
                    float sg = (col & 1) ? 1.f : -1.f;
                    #pragma unroll
                    for (int j = 0; j < 4; ++j) {
                        int row = m0 + wm + m * 16 + lg * 4 + j;
                        float v  = acc[m][n][j];
                        float pr = __shfl_xor(v, 1);
                        float o  = v * cosT[row * 64 + p] + sg * sinT[row * 64 + p] * pr;
                        C[(size_t)row * ldc2 + col] = f2bf(o);
                    }
                }
        } else {
            unsigned short* VT = (unsigned short*)Cp3;
            #pragma unroll
            for (int m = 0; m < 4; ++m)
                #pragma unroll
                for (int n = 0; n < 4; ++n) {
                    int col = n0 + wn + n * 16 + lr - 5120;
                    int r0  = m0 + wm + m * 16 + lg * 4;
                    ushort4 u;
                    u.x = f2bf(acc[m][n][0]); u.y = f2bf(acc[m][n][1]);
                    u.z = f2bf(acc[m][n][2]); u.w = f2bf(acc[m][n][3]);
                    *reinterpret_cast<ushort4*>(&VT[(size_t)col * SEQ + r0]) = u;
                }
        }
    }
}

// ---------------------------------------------------------------------------
// Flash attention, causal, fixed-max softmax.
// Block = (128 q rows, head), 8 waves x 16 q rows. KVBLK=64.
// K/V double-buffered in LDS via global_load_lds with pre-swizzled per-lane
// global source (linear DMA dest + XOR-swizzled read). 1 barrier per tile.
// ---------------------------------------------------------------------------
__global__ __launch_bounds__(512, 4) void attn_kernel(const unsigned short* __restrict__ Qb,
                                                      const unsigned short* __restrict__ Kb,
                                                      const unsigned short* __restrict__ Vt,
                                                      unsigned short* __restrict__ Ob)
{
    __shared__ unsigned short Kl[2][64 * 128];
    __shared__ unsigned short Vl[2][128 * 64];
    __shared__ unsigned short Pl[8][16 * 64];

    const int t  = threadIdx.x;
    const int w  = t >> 6, l = t & 63;
    const int lr = l & 15, lg = l >> 4;
    const int qb = (gridDim.x - 1) - blockIdx.x;      // largest-work first
    const int h  = blockIdx.y;
    const int kvh = h >> 2;
    const int qw = qb * 128 + w * 16;

    bf16x8 qf[4];
    #pragma unroll
    for (int f = 0; f < 4; ++f)
        qf[f] = *reinterpret_cast<const bf16x8*>(Qb + (size_t)(qw + lr) * DIM + h * HD + f * 32 + lg * 8);

    f32x4 po[8] = {};
    float lsum[4] = {0.f, 0.f, 0.f, 0.f};
    const float scale = 0.08838834764831845f;   // 1/sqrt(128)
    const int nt = 2 * qb + 2;

    auto STAGE = [&](int kt, int b) {
        const int kbase = kt * 64;
        #pragma unroll
        for (int i = 0; i < 2; ++i) {
            int key = w * 8 + 4 * i + (l >> 4);
            const unsigned short* src = Kb + (size_t)(kbase + key) * KVDIM + kvh * HD
                                           + (((l & 15) ^ (key & 7)) << 3);
            __builtin_amdgcn_global_load_lds(
                (const __attribute__((address_space(1))) void*)src,
                (__attribute__((address_space(3))) void*)&Kl[b][(w * 8 + 4 * i) * 128],
                16, 0, 0);
        }
        #pragma unroll
        for (int i = 0; i < 2; ++i) {
            int d = w * 16 + 8 * i + (l >> 3);
            const unsigned short* src = Vt + (size_t)(kvh * HD + d) * SEQ + kbase
                                           + (((l & 7) ^ (d & 7)) << 3);
            __builtin_amdgcn_global_load_lds(
                (const __attribute__((address_space(1))) void*)src,
                (__attribute__((address_space(3))) void*)&Vl[b][(w * 16 + 8 * i) * 64],
                16, 0, 0);
        }
    };

    STAGE(0, 0);
    __syncthreads();
    int cur = 0;

    for (int kt = 0; kt < nt; ++kt) {
        const int kbase = kt * 64;
        if (kt + 1 < nt) STAGE(kt + 1, cur ^ 1);

        if (kbase <= qw + 15) {
            // ---- QK^T: 16q x 64k ----
            f32x4 sc[4] = {};
            #pragma unroll
            for (int c = 0; c < 4; ++c) {
                int key = c * 16 + lr;
                #pragma unroll
                for (int f = 0; f < 4; ++f) {
                    bf16x8 kb = *reinterpret_cast<const bf16x8*>(
                        &Kl[cur][(key * 128 + f * 32 + lg * 8) ^ ((key & 7) << 3)]);
                    sc[c] = __builtin_amdgcn_mfma_f32_16x16x32_bf16(qf[f], kb, sc[c], 0, 0, 0);
                }
            }

            // ---- fixed-max softmax: p = exp(s*scale - 8), no cross-lane ----
            const bool diag = (kbase + 63 > qw);
            #pragma unroll
            for (int j = 0; j < 4; ++j) {
                int q = qw + lg * 4 + j;
                int prow = lg * 4 + j;
                float ps = 0.f;
                #pragma unroll
                for (int c = 0; c < 4; ++c) {
                    float p = __expf(sc[c][j] * scale - 8.0f);
                    if (diag && (kbase + c * 16 + lr > q)) p = 0.f;
                    ps += p;
                    Pl[w][(prow * 64 + c * 16 + lr) ^ ((prow & 7) << 3)] = f2bf(p);
                }
                lsum[j] += ps;
            }

            // ---- PV ----
            bf16x8 pa0 = *reinterpret_cast<const bf16x8*>(
                &Pl[w][(lr * 64 + lg * 8) ^ ((lr & 7) << 3)]);
            bf16x8 pa1 = *reinterpret_cast<const bf16x8*>(
                &Pl[w][(lr * 64 + 32 + lg * 8) ^ ((lr & 7) << 3)]);
            #pragma unroll
            for (int o = 0; o < 8; ++o) {
                int d = o * 16 + lr;
                bf16x8 bv0 = *reinterpret_cast<const bf16x8*>(
                    &Vl[cur][(d * 64 + lg * 8) ^ ((d & 7) << 3)]);
                bf16x8 bv1 = *reinterpret_cast<const bf16x8*>(
                    &Vl[cur][(d * 64 + 32 + lg * 8) ^ ((d & 7) << 3)]);
                po[o] = __builtin_amdgcn_mfma_f32_16x16x32_bf16(pa0, bv0, po[o], 0, 0, 0);
                po[o] = __builtin_amdgcn_mfma_f32_16x16x32_bf16(pa1, bv1, po[o], 0, 0, 0);
            }
        }
        __syncthreads();     // waves done with buf[cur]; buf[cur^1] loads drained
        cur ^= 1;
    }

    // ---- epilogue: one deferred row-sum reduce, then normalize ----
    #pragma unroll
    for (int j = 0; j < 4; ++j) {
        float s = lsum[j];
        s += __shfl_xor(s, 1);
        s += __shfl_xor(s, 2);
        s += __shfl_xor(s, 4);
        s += __shfl_xor(s, 8);
        float inv = 1.f / s;
        int q = qw + lg * 4 + j;
        #pragma unroll
        for (int o = 0; o < 8; ++o)
            Ob[(size_t)q * DIM + h * HD + o * 16 + lr] = f2bf(po[o][j] * inv);
    }
}

// ---------------------------------------------------------------------------
extern "C" void kernel_launch(void* const* d_in, const int* in_sizes, int n_in,
                              void* d_out, int out_size, void* d_ws, size_t ws_size,
                              hipStream_t stream) {
    const float* x    = (const float*)d_in[0];
    const float* wq   = (const float*)d_in[1];
    const float* wk   = (const float*)d_in[2];
    const float* wv   = (const float*)d_in[3];
    const float* wo   = (const float*)d_in[4];
    const float* cosT = (const float*)d_in[5];
    const float* sinT = (const float*)d_in[6];
    float* out = (float*)d_out;

    unsigned short* ws = (unsigned short*)d_ws;
    const bool big = ws_size >= (size_t)136 * 1024 * 1024;

    if (big) {
        unsigned short* xb   = ws;                                   // 2048x4096
        unsigned short* wqkv = xb   + (size_t)SEQ * DIM;             // 6144x4096 (wq|wk|wv)
        unsigned short* wob  = wqkv + (size_t)(DIM + 2 * KVDIM) * DIM; // 4096x4096
        unsigned short* Qb   = wob  + (size_t)DIM * DIM;             // 2048x4096
        unsigned short* Kb   = Qb   + (size_t)SEQ * DIM;             // 2048x1024
        unsigned short* Vtb  = Kb   + (size_t)SEQ * KVDIM;           // 1024x2048 (transposed)
        unsigned short* Ob   = Vtb  + (size_t)KVDIM * SEQ;           // 2048x4096

        cvt5_kernel<<<2048, 256, 0, stream>>>(x, wq, wk, wv, wo, ws);

        gemm_bt<true, true, 5><<<dim3(48, 16), 256, 0, stream>>>(
            xb, wqkv, Qb, Kb, Vtb, 0, cosT, sinT);
        attn_kernel<<<dim3(16, 32), 512, 0, stream>>>(Qb, Kb, Vtb, Ob);
        gemm_bt<true, true, 3><<<dim3(32, 16), 256, 0, stream>>>(
            Ob, wob, out, nullptr, nullptr, DIM, nullptr, nullptr);
    } else {
        unsigned short* Qb  = ws;
        unsigned short* Kb  = Qb  + (size_t)SEQ * DIM;
        unsigned short* Vtb = Kb  + (size_t)SEQ * KVDIM;
        unsigned short* Ob  = Vtb + (size_t)KVDIM * SEQ;

        gemm_bt<false, false, 1><<<dim3(32, 16), 256, 0, stream>>>(
            x, wq, Qb, nullptr, nullptr, DIM, cosT, sinT);
        gemm_bt<false, false, 1><<<dim3(8, 16),  256, 0, stream>>>(
            x, wk, Kb, nullptr, nullptr, KVDIM, cosT, sinT);
        gemm_bt<false, false, 2><<<dim3(8, 16),  256, 0, stream>>>(
            x, wv, Vtb, nullptr, nullptr, 0, nullptr, nullptr);
        attn_kernel<<<dim3(16, 32), 512, 0, stream>>>(Qb, Kb, Vtb, Ob);
        gemm_bt<true, false, 3><<<dim3(32, 16), 256, 0, stream>>>(
            Ob, wo, out, nullptr, nullptr, DIM, nullptr, nullptr);
    }
}

// Round 12
// 613.877 us; speedup vs baseline: 1.0400x; 1.0400x over previous
//
#include <hip/hip_runtime.h>

#define SEQ   2048
#define DIM   4096
#define NH    32
#define NKV   8
#define HD    128
#define KVDIM 1024   // NKV*HD

typedef __attribute__((ext_vector_type(8))) short bf16x8;
typedef __attribute__((ext_vector_type(4))) float f32x4;

static __device__ __forceinline__ unsigned short f2bf(float x) {
    unsigned int u = __float_as_uint(x);
    unsigned int r = (u + 0x7fffu + ((u >> 16) & 1u)) >> 16;   // RNE
    return (unsigned short)r;
}

// ---------------------------------------------------------------------------
// Fused fp32 -> bf16 convert of x|wq|wk|wv|wo into the contiguous ws region
// [xb][wq][wk][wv][wo]. One launch, grid-stride, float4/ushort4.
// ---------------------------------------------------------------------------
#define B0_4   2097152   // 2048*4096/4
#define B1_4   6291456   // +4096*4096/4
#define B2_4   7340032   // +1024*4096/4
#define B3_4   8388608   // +1024*4096/4
#define TOT4  12582912   // +4096*4096/4

__global__ __launch_bounds__(256) void cvt5_kernel(const float* __restrict__ x,
                                                   const float* __restrict__ wq,
                                                   const float* __restrict__ wk,
                                                   const float* __restrict__ wv,
                                                   const float* __restrict__ wo,
                                                   unsigned short* __restrict__ d)
{
    int i = blockIdx.x * 256 + threadIdx.x;
    const int stride = gridDim.x * 256;
    for (; i < TOT4; i += stride) {
        const float* s; int off;
        if      (i < B0_4) { s = x;  off = i;         }
        else if (i < B1_4) { s = wq; off = i - B0_4;  }
        else if (i < B2_4) { s = wk; off = i - B1_4;  }
        else if (i < B3_4) { s = wv; off = i - B2_4;  }
        else               { s = wo; off = i - B3_4;  }
        float4 v = reinterpret_cast<const float4*>(s)[off];
        ushort4 u;
        u.x = f2bf(v.x); u.y = f2bf(v.y); u.z = f2bf(v.z); u.w = f2bf(v.w);
        reinterpret_cast<ushort4*>(d)[i] = u;
    }
}

// fp32 -> bf16 bulk convert (fallback path only)
__global__ __launch_bounds__(256) void cvt_kernel(const float* __restrict__ s,
                                                  unsigned short* __restrict__ d, int n4)
{
    int i = blockIdx.x * 256 + threadIdx.x;
    int stride = gridDim.x * 256;
    for (; i < n4; i += stride) {
        float4 v = reinterpret_cast<const float4*>(s)[i];
        ushort4 u;
        u.x = f2bf(v.x); u.y = f2bf(v.y); u.z = f2bf(v.z); u.w = f2bf(v.w);
        reinterpret_cast<ushort4*>(d)[i] = u;
    }
}

// ---------------------------------------------------------------------------
// GEMM: C[M,N] = A[M,4096] . W[N,4096]^T
// 128x128 tile, BK=32, 4 waves (2x2), wave 64x64 = 4x4 MFMA 16x16x32.
// bf16 operands (ABF&&WBF): double-buffered LDS + global_load_lds prefetch,
//   statically unrolled 2x (buffer index is a literal), 1 barrier / K-step.
// fp32 operand: reg-staged convert into padded LDS (2-barrier, fallback).
// MODE: 1 = bf16 out + fused RoPE      2 = bf16 out transposed
//       3 = fp32 out (LDS-bounced coalesced float4 stores on DB path)
//       5 = fused QKV: n0<4096 Q-RoPE->Cp, n0<5120 K-RoPE->Cp2, else V^T->Cp3
// ---------------------------------------------------------------------------
template<bool ABF, bool WBF, int MODE>
__global__ __launch_bounds__(256) void gemm_bt(
    const void* __restrict__ Ap, const void* __restrict__ Wp,
    void* __restrict__ Cp, void* __restrict__ Cp2, void* __restrict__ Cp3, int ldC,
    const float* __restrict__ cosT, const float* __restrict__ sinT)
{
    constexpr bool DB = ABF && WBF;
    constexpr int AS = ABF ? 32 : 40;
    constexpr int BS = WBF ? 32 : 40;
    __shared__ unsigned short As[DB ? 2 : 1][128 * AS];
    __shared__ unsigned short Bs[DB ? 2 : 1][128 * BS];

    const int t  = threadIdx.x;
    const int w  = t >> 6, l = t & 63;
    const int lr = l & 15, lg = l >> 4;
    const int wm = (w >> 1) * 64, wn = (w & 1) * 64;
    const int m0 = blockIdx.y * 128, n0 = blockIdx.x * 128;

    f32x4 acc[4][4] = {};

    if constexpr (DB) {
        const unsigned short* A = (const unsigned short*)Ap;
        const unsigned short* B = (const unsigned short*)Wp;

        auto STAGE = [&](int k0, int b) {
            #pragma unroll
            for (int i = 0; i < 2; ++i) {
                const unsigned short* src =
                    A + (size_t)(m0 + i * 64 + w * 16 + (l >> 2)) * 4096 + k0 + (l & 3) * 8;
                __builtin_amdgcn_global_load_lds(
                    (const __attribute__((address_space(1))) void*)src,
                    (__attribute__((address_space(3))) void*)&As[b][(i * 64 + w * 16) * 32],
                    16, 0, 0);
            }
            #pragma unroll
            for (int i = 0; i < 2; ++i) {
                const unsigned short* src =
                    B + (size_t)(n0 + i * 64 + w * 16 + (l >> 2)) * 4096 + k0 + (l & 3) * 8;
                __builtin_amdgcn_global_load_lds(
                    (const __attribute__((address_space(1))) void*)src,
                    (__attribute__((address_space(3))) void*)&Bs[b][(i * 64 + w * 16) * 32],
                    16, 0, 0);
            }
        };
        auto COMPUTE = [&](int b) {
            bf16x8 af[4], bfr[4];
            #pragma unroll
            for (int m = 0; m < 4; ++m)
                af[m] = *reinterpret_cast<const bf16x8*>(&As[b][(wm + m * 16 + lr) * 32 + lg * 8]);
            #pragma unroll
            for (int n = 0; n < 4; ++n)
                bfr[n] = *reinterpret_cast<const bf16x8*>(&Bs[b][(wn + n * 16 + lr) * 32 + lg * 8]);
            #pragma unroll
            for (int m = 0; m < 4; ++m)
                #pragma unroll
                for (int n = 0; n < 4; ++n)
                    acc[m][n] = __builtin_amdgcn_mfma_f32_16x16x32_bf16(af[m], bfr[n], acc[m][n], 0, 0, 0);
        };

        STAGE(0, 0);
        __syncthreads();
        for (int k0 = 0; k0 < 4096; k0 += 64) {
            STAGE(k0 + 32, 1);                 // always valid: k0+32 <= 4064
            COMPUTE(0);
            __syncthreads();                   // drains STAGE(..,1) before reading buf 1
            if (k0 + 64 < 4096) STAGE(k0 + 64, 0);
            COMPUTE(1);
            __syncthreads();                   // drains STAGE(..,0) before next iter
        }
    } else {
        for (int k0 = 0; k0 < 4096; k0 += 32) {
            {
                const float* A = (const float*)Ap;
                #pragma unroll
                for (int i = 0; i < 4; ++i) {
                    int row = (t >> 3) + 32 * i, kc = (t & 7) * 4;
                    float4 v = *reinterpret_cast<const float4*>(A + (size_t)(m0 + row) * 4096 + k0 + kc);
                    ushort4 u;
                    u.x = f2bf(v.x); u.y = f2bf(v.y); u.z = f2bf(v.z); u.w = f2bf(v.w);
                    *reinterpret_cast<ushort4*>(&As[0][row * 40 + kc]) = u;
                }
            }
            {
                const float* B = (const float*)Wp;
                #pragma unroll
                for (int i = 0; i < 4; ++i) {
                    int row = (t >> 3) + 32 * i, kc = (t & 7) * 4;
                    float4 v = *reinterpret_cast<const float4*>(B + (size_t)(n0 + row) * 4096 + k0 + kc);
                    ushort4 u;
                    u.x = f2bf(v.x); u.y = f2bf(v.y); u.z = f2bf(v.z); u.w = f2bf(v.w);
                    *reinterpret_cast<ushort4*>(&Bs[0][row * 40 + kc]) = u;
                }
            }
            __syncthreads();

            bf16x8 af[4], bfr[4];
            #pragma unroll
            for (int m = 0; m < 4; ++m)
                af[m] = *reinterpret_cast<const bf16x8*>(&As[0][(wm + m * 16 + lr) * AS + lg * 8]);
            #pragma unroll
            for (int n = 0; n < 4; ++n)
                bfr[n] = *reinterpret_cast<const bf16x8*>(&Bs[0][(wn + n * 16 + lr) * BS + lg * 8]);
            #pragma unroll
            for (int m = 0; m < 4; ++m)
                #pragma unroll
                for (int n = 0; n < 4; ++n)
                    acc[m][n] = __builtin_amdgcn_mfma_f32_16x16x32_bf16(af[m], bfr[n], acc[m][n], 0, 0, 0);
            __syncthreads();
        }
    }

    // ---- epilogues ----
    if constexpr (MODE == 3) {
        float* C = (float*)Cp;
        if constexpr (DB) {
            // LDS-bounce: 4 chunks of 32 rows through As (16 KB), coalesced f4 out
            float* Cl = reinterpret_cast<float*>(&As[0][0]);
            #pragma unroll
            for (int chunk = 0; chunk < 4; ++chunk) {
                __syncthreads();
                int mb = chunk * 32 - wm;            // 0 or 32 for owning waves
                if (mb == 0 || mb == 32) {
                    #pragma unroll
                    for (int mm = 0; mm < 2; ++mm) {
                        int m = (mb >> 4) + mm;
                        #pragma unroll
                        for (int n = 0; n < 4; ++n) {
                            int col = wn + n * 16 + lr;
                            #pragma unroll
                            for (int j = 0; j < 4; ++j)
                                Cl[(mm * 16 + lg * 4 + j) * 128 + col] = acc[m][n][j];
                        }
                    }
                }
                __syncthreads();
                #pragma unroll
                for (int p = 0; p < 4; ++p) {
                    int r  = (t >> 5) + p * 8;
                    int cc = (t & 31) * 4;
                    float4 v = *reinterpret_cast<const float4*>(&Cl[r * 128 + cc]);
                    *reinterpret_cast<float4*>(
                        &C[(size_t)(m0 + chunk * 32 + r) * ldC + n0 + cc]) = v;
                }
            }
        } else {
            #pragma unroll
            for (int m = 0; m < 4; ++m)
                #pragma unroll
                for (int n = 0; n < 4; ++n)
                    #pragma unroll
                    for (int j = 0; j < 4; ++j)
                        C[(size_t)(m0 + wm + m * 16 + lg * 4 + j) * ldC + n0 + wn + n * 16 + lr] =
                            acc[m][n][j];
        }
    } else if constexpr (MODE == 2) {
        unsigned short* VT = (unsigned short*)Cp;
        #pragma unroll
        for (int m = 0; m < 4; ++m)
            #pragma unroll
            for (int n = 0; n < 4; ++n) {
                int col = n0 + wn + n * 16 + lr;
                int r0  = m0 + wm + m * 16 + lg * 4;
                ushort4 u;
                u.x = f2bf(acc[m][n][0]); u.y = f2bf(acc[m][n][1]);
                u.z = f2bf(acc[m][n][2]); u.w = f2bf(acc[m][n][3]);
                *reinterpret_cast<ushort4*>(&VT[(size_t)col * SEQ + r0]) = u;
            }
    } else if constexpr (MODE == 1) {
        unsigned short* C = (unsigned short*)Cp;
        #pragma unroll
        for (int m = 0; m < 4; ++m)
            #pragma unroll
            for (int n = 0; n < 4; ++n) {
                int col = n0 + wn + n * 16 + lr;
                int p   = (col & 127) >> 1;
                float sg = (col & 1) ? 1.f : -1.f;
                #pragma unroll
                for (int j = 0; j < 4; ++j) {
                    int row = m0 + wm + m * 16 + lg * 4 + j;
                    float v  = acc[m][n][j];
                    float pr = __shfl_xor(v, 1);
                    float o  = v * cosT[row * 64 + p] + sg * sinT[row * 64 + p] * pr;
                    C[(size_t)row * ldC + col] = f2bf(o);
                }
            }
    } else {  // MODE 5: fused QKV
        if (n0 < 5120) {
            unsigned short* C;
            int ldc2, csub;
            if (n0 < 4096) { C = (unsigned short*)Cp;  ldc2 = DIM;   csub = 0;    }
            else           { C = (unsigned short*)Cp2; ldc2 = KVDIM; csub = 4096; }
            #pragma unroll
            for (int m = 0; m < 4; ++m)
                #pragma unroll
                for (int n = 0; n < 4; ++n) {
                    int col = n0 + wn + n * 16 + lr - csub;
                    int p   = (col & 127) >> 1;
                    float sg = (col & 1) ? 1.f : -1.f;
                    #pragma unroll
                    for (int j = 0; j < 4; ++j) {
                        int row = m0 + wm + m * 16 + lg * 4 + j;
                        float v  = acc[m][n][j];
                        float pr = __shfl_xor(v, 1);
                        float o  = v * cosT[row * 64 + p] + sg * sinT[row * 64 + p] * pr;
                        C[(size_t)row * ldc2 + col] = f2bf(o);
                    }
                }
        } else {
            unsigned short* VT = (unsigned short*)Cp3;
            #pragma unroll
            for (int m = 0; m < 4; ++m)
                #pragma unroll
                for (int n = 0; n < 4; ++n) {
                    int col = n0 + wn + n * 16 + lr - 5120;
                    int r0  = m0 + wm + m * 16 + lg * 4;
                    ushort4 u;
                    u.x = f2bf(acc[m][n][0]); u.y = f2bf(acc[m][n][1]);
                    u.z = f2bf(acc[m][n][2]); u.w = f2bf(acc[m][n][3]);
                    *reinterpret_cast<ushort4*>(&VT[(size_t)col * SEQ + r0]) = u;
                }
        }
    }
}

// ---------------------------------------------------------------------------
// Flash attention, causal, fixed-max softmax.
// Block = (128 q rows, head), 8 waves x 16 q rows. KVBLK=64.
// K/V double-buffered in LDS via global_load_lds with pre-swizzled per-lane
// global source (linear DMA dest + XOR-swizzled read). 1 barrier per tile.
// ---------------------------------------------------------------------------
__global__ __launch_bounds__(512, 4) void attn_kernel(const unsigned short* __restrict__ Qb,
                                                      const unsigned short* __restrict__ Kb,
                                                      const unsigned short* __restrict__ Vt,
                                                      unsigned short* __restrict__ Ob)
{
    __shared__ unsigned short Kl[2][64 * 128];
    __shared__ unsigned short Vl[2][128 * 64];
    __shared__ unsigned short Pl[8][16 * 64];

    const int t  = threadIdx.x;
    const int w  = t >> 6, l = t & 63;
    const int lr = l & 15, lg = l >> 4;
    const int qb = (gridDim.x - 1) - blockIdx.x;      // largest-work first
    const int h  = blockIdx.y;
    const int kvh = h >> 2;
    const int qw = qb * 128 + w * 16;

    bf16x8 qf[4];
    #pragma unroll
    for (int f = 0; f < 4; ++f)
        qf[f] = *reinterpret_cast<const bf16x8*>(Qb + (size_t)(qw + lr) * DIM + h * HD + f * 32 + lg * 8);

    f32x4 po[8] = {};
    float lsum[4] = {0.f, 0.f, 0.f, 0.f};
    const float scale = 0.08838834764831845f;   // 1/sqrt(128)
    const int nt = 2 * qb + 2;

    auto STAGE = [&](int kt, int b) {
        const int kbase = kt * 64;
        #pragma unroll
        for (int i = 0; i < 2; ++i) {
            int key = w * 8 + 4 * i + (l >> 4);
            const unsigned short* src = Kb + (size_t)(kbase + key) * KVDIM + kvh * HD
                                           + (((l & 15) ^ (key & 7)) << 3);
            __builtin_amdgcn_global_load_lds(
                (const __attribute__((address_space(1))) void*)src,
                (__attribute__((address_space(3))) void*)&Kl[b][(w * 8 + 4 * i) * 128],
                16, 0, 0);
        }
        #pragma unroll
        for (int i = 0; i < 2; ++i) {
            int d = w * 16 + 8 * i + (l >> 3);
            const unsigned short* src = Vt + (size_t)(kvh * HD + d) * SEQ + kbase
                                           + (((l & 7) ^ (d & 7)) << 3);
            __builtin_amdgcn_global_load_lds(
                (const __attribute__((address_space(1))) void*)src,
                (__attribute__((address_space(3))) void*)&Vl[b][(w * 16 + 8 * i) * 64],
                16, 0, 0);
        }
    };

    STAGE(0, 0);
    __syncthreads();
    int cur = 0;

    for (int kt = 0; kt < nt; ++kt) {
        const int kbase = kt * 64;
        if (kt + 1 < nt) STAGE(kt + 1, cur ^ 1);

        if (kbase <= qw + 15) {
            // ---- QK^T: 16q x 64k ----
            f32x4 sc[4] = {};
            #pragma unroll
            for (int c = 0; c < 4; ++c) {
                int key = c * 16 + lr;
                #pragma unroll
                for (int f = 0; f < 4; ++f) {
                    bf16x8 kb = *reinterpret_cast<const bf16x8*>(
                        &Kl[cur][(key * 128 + f * 32 + lg * 8) ^ ((key & 7) << 3)]);
                    sc[c] = __builtin_amdgcn_mfma_f32_16x16x32_bf16(qf[f], kb, sc[c], 0, 0, 0);
                }
            }

            // ---- fixed-max softmax: p = exp(s*scale - 8), no cross-lane ----
            const bool diag = (kbase + 63 > qw);
            #pragma unroll
            for (int j = 0; j < 4; ++j) {
                int q = qw + lg * 4 + j;
                int prow = lg * 4 + j;
                float ps = 0.f;
                #pragma unroll
                for (int c = 0; c < 4; ++c) {
                    float p = __expf(sc[c][j] * scale - 8.0f);
                    if (diag && (kbase + c * 16 + lr > q)) p = 0.f;
                    ps += p;
                    Pl[w][(prow * 64 + c * 16 + lr) ^ ((prow & 7) << 3)] = f2bf(p);
                }
                lsum[j] += ps;
            }

            // ---- PV ----
            bf16x8 pa0 = *reinterpret_cast<const bf16x8*>(
                &Pl[w][(lr * 64 + lg * 8) ^ ((lr & 7) << 3)]);
            bf16x8 pa1 = *reinterpret_cast<const bf16x8*>(
                &Pl[w][(lr * 64 + 32 + lg * 8) ^ ((lr & 7) << 3)]);
            #pragma unroll
            for (int o = 0; o < 8; ++o) {
                int d = o * 16 + lr;
                bf16x8 bv0 = *reinterpret_cast<const bf16x8*>(
                    &Vl[cur][(d * 64 + lg * 8) ^ ((d & 7) << 3)]);
                bf16x8 bv1 = *reinterpret_cast<const bf16x8*>(
                    &Vl[cur][(d * 64 + 32 + lg * 8) ^ ((d & 7) << 3)]);
                po[o] = __builtin_amdgcn_mfma_f32_16x16x32_bf16(pa0, bv0, po[o], 0, 0, 0);
                po[o] = __builtin_amdgcn_mfma_f32_16x16x32_bf16(pa1, bv1, po[o], 0, 0, 0);
            }
        }
        __syncthreads();     // waves done with buf[cur]; buf[cur^1] loads drained
        cur ^= 1;
    }

    // ---- epilogue: one deferred row-sum reduce, then normalize ----
    #pragma unroll
    for (int j = 0; j < 4; ++j) {
        float s = lsum[j];
        s += __shfl_xor(s, 1);
        s += __shfl_xor(s, 2);
        s += __shfl_xor(s, 4);
        s += __shfl_xor(s, 8);
        float inv = 1.f / s;
        int q = qw + lg * 4 + j;
        #pragma unroll
        for (int o = 0; o < 8; ++o)
            Ob[(size_t)q * DIM + h * HD + o * 16 + lr] = f2bf(po[o][j] * inv);
    }
}

// ---------------------------------------------------------------------------
extern "C" void kernel_launch(void* const* d_in, const int* in_sizes, int n_in,
                              void* d_out, int out_size, void* d_ws, size_t ws_size,
                              hipStream_t stream) {
    const float* x    = (const float*)d_in[0];
    const float* wq   = (const float*)d_in[1];
    const float* wk   = (const float*)d_in[2];
    const float* wv   = (const float*)d_in[3];
    const float* wo   = (const float*)d_in[4];
    const float* cosT = (const float*)d_in[5];
    const float* sinT = (const float*)d_in[6];
    float* out = (float*)d_out;

    unsigned short* ws = (unsigned short*)d_ws;
    const bool big = ws_size >= (size_t)136 * 1024 * 1024;

    if (big) {
        unsigned short* xb   = ws;                                   // 2048x4096
        unsigned short* wqkv = xb   + (size_t)SEQ * DIM;             // 6144x4096 (wq|wk|wv)
        unsigned short* wob  = wqkv + (size_t)(DIM + 2 * KVDIM) * DIM; // 4096x4096
        unsigned short* Qb   = wob  + (size_t)DIM * DIM;             // 2048x4096
        unsigned short* Kb   = Qb   + (size_t)SEQ * DIM;             // 2048x1024
        unsigned short* Vtb  = Kb   + (size_t)SEQ * KVDIM;           // 1024x2048 (transposed)
        unsigned short* Ob   = Vtb  + (size_t)KVDIM * SEQ;           // 2048x4096

        cvt5_kernel<<<2048, 256, 0, stream>>>(x, wq, wk, wv, wo, ws);

        gemm_bt<true, true, 5><<<dim3(48, 16), 256, 0, stream>>>(
            xb, wqkv, Qb, Kb, Vtb, 0, cosT, sinT);
        attn_kernel<<<dim3(16, 32), 512, 0, stream>>>(Qb, Kb, Vtb, Ob);
        gemm_bt<true, true, 3><<<dim3(32, 16), 256, 0, stream>>>(
            Ob, wob, out, nullptr, nullptr, DIM, nullptr, nullptr);
    } else {
        unsigned short* Qb  = ws;
        unsigned short* Kb  = Qb  + (size_t)SEQ * DIM;
        unsigned short* Vtb = Kb  + (size_t)SEQ * KVDIM;
        unsigned short* Ob  = Vtb + (size_t)KVDIM * SEQ;

        gemm_bt<false, false, 1><<<dim3(32, 16), 256, 0, stream>>>(
            x, wq, Qb, nullptr, nullptr, DIM, cosT, sinT);
        gemm_bt<false, false, 1><<<dim3(8, 16),  256, 0, stream>>>(
            x, wk, Kb, nullptr, nullptr, KVDIM, cosT, sinT);
        gemm_bt<false, false, 2><<<dim3(8, 16),  256, 0, stream>>>(
            x, wv, Vtb, nullptr, nullptr, 0, nullptr, nullptr);
        attn_kernel<<<dim3(16, 32), 512, 0, stream>>>(Qb, Kb, Vtb, Ob);
        gemm_bt<true, false, 3><<<dim3(32, 16), 256, 0, stream>>>(
            Ob, wo, out, nullptr, nullptr, DIM, nullptr, nullptr);
    }
}

// Round 13
// 604.270 us; speedup vs baseline: 1.0565x; 1.0159x over previous
//
#include <hip/hip_runtime.h>

#define SEQ   2048
#define DIM   4096
#define NH    32
#define NKV   8
#define HD    128
#define KVDIM 1024   // NKV*HD

typedef __attribute__((ext_vector_type(8))) short bf16x8;
typedef __attribute__((ext_vector_type(4))) float f32x4;

static __device__ __forceinline__ unsigned short f2bf(float x) {
    unsigned int u = __float_as_uint(x);
    unsigned int r = (u + 0x7fffu + ((u >> 16) & 1u)) >> 16;   // RNE
    return (unsigned short)r;
}

// ---------------------------------------------------------------------------
// Fused fp32 -> bf16 convert of x|wq|wk|wv|wo into the contiguous ws region
// ---------------------------------------------------------------------------
#define B0_4   2097152   // 2048*4096/4
#define B1_4   6291456   // +4096*4096/4
#define B2_4   7340032   // +1024*4096/4
#define B3_4   8388608   // +1024*4096/4
#define TOT4  12582912   // +4096*4096/4

__global__ __launch_bounds__(256) void cvt5_kernel(const float* __restrict__ x,
                                                   const float* __restrict__ wq,
                                                   const float* __restrict__ wk,
                                                   const float* __restrict__ wv,
                                                   const float* __restrict__ wo,
                                                   unsigned short* __restrict__ d)
{
    int i = blockIdx.x * 256 + threadIdx.x;
    const int stride = gridDim.x * 256;
    for (; i < TOT4; i += stride) {
        const float* s; int off;
        if      (i < B0_4) { s = x;  off = i;         }
        else if (i < B1_4) { s = wq; off = i - B0_4;  }
        else if (i < B2_4) { s = wk; off = i - B1_4;  }
        else if (i < B3_4) { s = wv; off = i - B2_4;  }
        else               { s = wo; off = i - B3_4;  }
        float4 v = reinterpret_cast<const float4*>(s)[off];
        ushort4 u;
        u.x = f2bf(v.x); u.y = f2bf(v.y); u.z = f2bf(v.z); u.w = f2bf(v.w);
        reinterpret_cast<ushort4*>(d)[i] = u;
    }
}

// fp32 -> bf16 bulk convert (fallback path only)
__global__ __launch_bounds__(256) void cvt_kernel(const float* __restrict__ s,
                                                  unsigned short* __restrict__ d, int n4)
{
    int i = blockIdx.x * 256 + threadIdx.x;
    int stride = gridDim.x * 256;
    for (; i < n4; i += stride) {
        float4 v = reinterpret_cast<const float4*>(s)[i];
        ushort4 u;
        u.x = f2bf(v.x); u.y = f2bf(v.y); u.z = f2bf(v.z); u.w = f2bf(v.w);
        reinterpret_cast<ushort4*>(d)[i] = u;
    }
}

// ---------------------------------------------------------------------------
// GEMM: C[M,N] = A[M,4096] . W[N,4096]^T
// 128x128 tile, BK=32, 4 waves (2x2), wave 64x64 = 4x4 MFMA 16x16x32.
// bf16 operands (DB path): 4-buffer LDS, depth-2 global_load_lds prefetch,
//   counted s_waitcnt vmcnt(8) + raw s_barrier per K-step (never vmcnt(0)
//   in the main loop); tail peeled with vmcnt(4)/vmcnt(0).
//   Interval p runs {COMPUTE(p-1): buf[(p-1)&3], STAGE(p+2): buf[(p+2)&3]},
//   delta=3 mod 4 -> no buffer aliasing; vmcnt(8) before barrier ensures
//   every wave's tile-p loads landed before any wave reads them.
// fp32 operand: reg-staged convert into padded LDS (2-barrier, fallback).
// MODE: 1 = bf16 out + fused RoPE      2 = bf16 out transposed
//       3 = fp32 out (LDS-bounced coalesced float4 stores on DB path)
//       5 = fused QKV: n0<4096 Q-RoPE->Cp, n0<5120 K-RoPE->Cp2, else V^T->Cp3
// ---------------------------------------------------------------------------
template<bool ABF, bool WBF, int MODE>
__global__ __launch_bounds__(256) void gemm_bt(
    const void* __restrict__ Ap, const void* __restrict__ Wp,
    void* __restrict__ Cp, void* __restrict__ Cp2, void* __restrict__ Cp3, int ldC,
    const float* __restrict__ cosT, const float* __restrict__ sinT)
{
    constexpr bool DB = ABF && WBF;
    constexpr int NB = DB ? 4 : 1;
    constexpr int AS = ABF ? 32 : 40;
    constexpr int BS = WBF ? 32 : 40;
    __shared__ unsigned short As[NB][128 * AS];
    __shared__ unsigned short Bs[NB][128 * BS];

    const int t  = threadIdx.x;
    const int w  = t >> 6, l = t & 63;
    const int lr = l & 15, lg = l >> 4;
    const int wm = (w >> 1) * 64, wn = (w & 1) * 64;
    const int m0 = blockIdx.y * 128, n0 = blockIdx.x * 128;

    f32x4 acc[4][4] = {};

    if constexpr (DB) {
        const unsigned short* A = (const unsigned short*)Ap;
        const unsigned short* B = (const unsigned short*)Wp;

        auto STAGE = [&](int k0, int b) {
            #pragma unroll
            for (int i = 0; i < 2; ++i) {
                const unsigned short* src =
                    A + (size_t)(m0 + i * 64 + w * 16 + (l >> 2)) * 4096 + k0 + (l & 3) * 8;
                __builtin_amdgcn_global_load_lds(
                    (const __attribute__((address_space(1))) void*)src,
                    (__attribute__((address_space(3))) void*)&As[b][(i * 64 + w * 16) * 32],
                    16, 0, 0);
            }
            #pragma unroll
            for (int i = 0; i < 2; ++i) {
                const unsigned short* src =
                    B + (size_t)(n0 + i * 64 + w * 16 + (l >> 2)) * 4096 + k0 + (l & 3) * 8;
                __builtin_amdgcn_global_load_lds(
                    (const __attribute__((address_space(1))) void*)src,
                    (__attribute__((address_space(3))) void*)&Bs[b][(i * 64 + w * 16) * 32],
                    16, 0, 0);
            }
        };
        auto COMPUTE = [&](int b) {
            bf16x8 af[4], bfr[4];
            #pragma unroll
            for (int m = 0; m < 4; ++m)
                af[m] = *reinterpret_cast<const bf16x8*>(&As[b][(wm + m * 16 + lr) * 32 + lg * 8]);
            #pragma unroll
            for (int n = 0; n < 4; ++n)
                bfr[n] = *reinterpret_cast<const bf16x8*>(&Bs[b][(wn + n * 16 + lr) * 32 + lg * 8]);
            #pragma unroll
            for (int m = 0; m < 4; ++m)
                #pragma unroll
                for (int n = 0; n < 4; ++n)
                    acc[m][n] = __builtin_amdgcn_mfma_f32_16x16x32_bf16(af[m], bfr[n], acc[m][n], 0, 0, 0);
        };

        // 128 K-steps of 32. Depth-2 prefetch, 4 buffers.
        STAGE(0, 0);
        STAGE(32, 1);
        for (int kt = 0; kt < 126; ++kt) {
            STAGE((kt + 2) * 32, (kt + 2) & 3);
            asm volatile("s_waitcnt vmcnt(8)" ::: "memory");   // tile kt landed
            __builtin_amdgcn_s_barrier();
            COMPUTE(kt & 3);
        }
        asm volatile("s_waitcnt vmcnt(4)" ::: "memory");       // tile 126 landed
        __builtin_amdgcn_s_barrier();
        COMPUTE(2);
        asm volatile("s_waitcnt vmcnt(0)" ::: "memory");       // tile 127 landed
        __builtin_amdgcn_s_barrier();
        COMPUTE(3);
    } else {
        for (int k0 = 0; k0 < 4096; k0 += 32) {
            {
                const float* A = (const float*)Ap;
                #pragma unroll
                for (int i = 0; i < 4; ++i) {
                    int row = (t >> 3) + 32 * i, kc = (t & 7) * 4;
                    float4 v = *reinterpret_cast<const float4*>(A + (size_t)(m0 + row) * 4096 + k0 + kc);
                    ushort4 u;
                    u.x = f2bf(v.x); u.y = f2bf(v.y); u.z = f2bf(v.z); u.w = f2bf(v.w);
                    *reinterpret_cast<ushort4*>(&As[0][row * 40 + kc]) = u;
                }
            }
            {
                const float* B = (const float*)Wp;
                #pragma unroll
                for (int i = 0; i < 4; ++i) {
                    int row = (t >> 3) + 32 * i, kc = (t & 7) * 4;
                    float4 v = *reinterpret_cast<const float4*>(B + (size_t)(n0 + row) * 4096 + k0 + kc);
                    ushort4 u;
                    u.x = f2bf(v.x); u.y = f2bf(v.y); u.z = f2bf(v.z); u.w = f2bf(v.w);
                    *reinterpret_cast<ushort4*>(&Bs[0][row * 40 + kc]) = u;
                }
            }
            __syncthreads();

            bf16x8 af[4], bfr[4];
            #pragma unroll
            for (int m = 0; m < 4; ++m)
                af[m] = *reinterpret_cast<const bf16x8*>(&As[0][(wm + m * 16 + lr) * AS + lg * 8]);
            #pragma unroll
            for (int n = 0; n < 4; ++n)
                bfr[n] = *reinterpret_cast<const bf16x8*>(&Bs[0][(wn + n * 16 + lr) * BS + lg * 8]);
            #pragma unroll
            for (int m = 0; m < 4; ++m)
                #pragma unroll
                for (int n = 0; n < 4; ++n)
                    acc[m][n] = __builtin_amdgcn_mfma_f32_16x16x32_bf16(af[m], bfr[n], acc[m][n], 0, 0, 0);
            __syncthreads();
        }
    }

    // ---- epilogues ----
    if constexpr (MODE == 3) {
        float* C = (float*)Cp;
        if constexpr (DB) {
            // LDS-bounce: 4 chunks of 32 rows through As[0..1] (16 KB), f4 out
            float* Cl = reinterpret_cast<float*>(&As[0][0]);
            #pragma unroll
            for (int chunk = 0; chunk < 4; ++chunk) {
                __syncthreads();
                int mb = chunk * 32 - wm;            // 0 or 32 for owning waves
                if (mb == 0 || mb == 32) {
                    #pragma unroll
                    for (int mm = 0; mm < 2; ++mm) {
                        int m = (mb >> 4) + mm;
                        #pragma unroll
                        for (int n = 0; n < 4; ++n) {
                            int col = wn + n * 16 + lr;
                            #pragma unroll
                            for (int j = 0; j < 4; ++j)
                                Cl[(mm * 16 + lg * 4 + j) * 128 + col] = acc[m][n][j];
                        }
                    }
                }
                __syncthreads();
                #pragma unroll
                for (int p = 0; p < 4; ++p) {
                    int r  = (t >> 5) + p * 8;
                    int cc = (t & 31) * 4;
                    float4 v = *reinterpret_cast<const float4*>(&Cl[r * 128 + cc]);
                    *reinterpret_cast<float4*>(
                        &C[(size_t)(m0 + chunk * 32 + r) * ldC + n0 + cc]) = v;
                }
            }
        } else {
            #pragma unroll
            for (int m = 0; m < 4; ++m)
                #pragma unroll
                for (int n = 0; n < 4; ++n)
                    #pragma unroll
                    for (int j = 0; j < 4; ++j)
                        C[(size_t)(m0 + wm + m * 16 + lg * 4 + j) * ldC + n0 + wn + n * 16 + lr] =
                            acc[m][n][j];
        }
    } else if constexpr (MODE == 2) {
        unsigned short* VT = (unsigned short*)Cp;
        #pragma unroll
        for (int m = 0; m < 4; ++m)
            #pragma unroll
            for (int n = 0; n < 4; ++n) {
                int col = n0 + wn + n * 16 + lr;
                int r0  = m0 + wm + m * 16 + lg * 4;
                ushort4 u;
                u.x = f2bf(acc[m][n][0]); u.y = f2bf(acc[m][n][1]);
                u.z = f2bf(acc[m][n][2]); u.w = f2bf(acc[m][n][3]);
                *reinterpret_cast<ushort4*>(&VT[(size_t)col * SEQ + r0]) = u;
            }
    } else if constexpr (MODE == 1) {
        unsigned short* C = (unsigned short*)Cp;
        #pragma unroll
        for (int m = 0; m < 4; ++m)
            #pragma unroll
            for (int n = 0; n < 4; ++n) {
                int col = n0 + wn + n * 16 + lr;
                int p   = (col & 127) >> 1;
                float sg = (col & 1) ? 1.f : -1.f;
                #pragma unroll
                for (int j = 0; j < 4; ++j) {
                    int row = m0 + wm + m * 16 + lg * 4 + j;
                    float v  = acc[m][n][j];
                    float pr = __shfl_xor(v, 1);
                    float o  = v * cosT[row * 64 + p] + sg * sinT[row * 64 + p] * pr;
                    C[(size_t)row * ldC + col] = f2bf(o);
                }
            }
    } else {  // MODE 5: fused QKV
        if (n0 < 5120) {
            unsigned short* C;
            int ldc2, csub;
            if (n0 < 4096) { C = (unsigned short*)Cp;  ldc2 = DIM;   csub = 0;    }
            else           { C = (unsigned short*)Cp2; ldc2 = KVDIM; csub = 4096; }
            #pragma unroll
            for (int m = 0; m < 4; ++m)
                #pragma unroll
                for (int n = 0; n < 4; ++n) {
                    int col = n0 + wn + n * 16 + lr - csub;
                    int p   = (col & 127) >> 1;
                    float sg = (col & 1) ? 1.f : -1.f;
                    #pragma unroll
                    for (int j = 0; j < 4; ++j) {
                        int row = m0 + wm + m * 16 + lg * 4 + j;
                        float v  = acc[m][n][j];
                        float pr = __shfl_xor(v, 1);
                        float o  = v * cosT[row * 64 + p] + sg * sinT[row * 64 + p] * pr;
                        C[(size_t)row * ldc2 + col] = f2bf(o);
                    }
                }
        } else {
            unsigned short* VT = (unsigned short*)Cp3;
            #pragma unroll
            for (int m = 0; m < 4; ++m)
                #pragma unroll
                for (int n = 0; n < 4; ++n) {
                    int col = n0 + wn + n * 16 + lr - 5120;
                    int r0  = m0 + wm + m * 16 + lg * 4;
                    ushort4 u;
                    u.x = f2bf(acc[m][n][0]); u.y = f2bf(acc[m][n][1]);
                    u.z = f2bf(acc[m][n][2]); u.w = f2bf(acc[m][n][3]);
                    *reinterpret_cast<ushort4*>(&VT[(size_t)col * SEQ + r0]) = u;
                }
        }
    }
}

// ---------------------------------------------------------------------------
// Flash attention, causal, fixed-max softmax.
// Block = (128 q rows, head), 8 waves x 16 q rows. KVBLK=64.
// K/V double-buffered in LDS via global_load_lds with pre-swizzled per-lane
// global source (linear DMA dest + XOR-swizzled read). 1 barrier per tile.
// ---------------------------------------------------------------------------
__global__ __launch_bounds__(512, 4) void attn_kernel(const unsigned short* __restrict__ Qb,
                                                      const unsigned short* __restrict__ Kb,
                                                      const unsigned short* __restrict__ Vt,
                                                      unsigned short* __restrict__ Ob)
{
    __shared__ unsigned short Kl[2][64 * 128];
    __shared__ unsigned short Vl[2][128 * 64];
    __shared__ unsigned short Pl[8][16 * 64];

    const int t  = threadIdx.x;
    const int w  = t >> 6, l = t & 63;
    const int lr = l & 15, lg = l >> 4;
    const int qb = (gridDim.x - 1) - blockIdx.x;      // largest-work first
    const int h  = blockIdx.y;
    const int kvh = h >> 2;
    const int qw = qb * 128 + w * 16;

    bf16x8 qf[4];
    #pragma unroll
    for (int f = 0; f < 4; ++f)
        qf[f] = *reinterpret_cast<const bf16x8*>(Qb + (size_t)(qw + lr) * DIM + h * HD + f * 32 + lg * 8);

    f32x4 po[8] = {};
    float lsum[4] = {0.f, 0.f, 0.f, 0.f};
    const float scale = 0.08838834764831845f;   // 1/sqrt(128)
    const int nt = 2 * qb + 2;

    auto STAGE = [&](int kt, int b) {
        const int kbase = kt * 64;
        #pragma unroll
        for (int i = 0; i < 2; ++i) {
            int key = w * 8 + 4 * i + (l >> 4);
            const unsigned short* src = Kb + (size_t)(kbase + key) * KVDIM + kvh * HD
                                           + (((l & 15) ^ (key & 7)) << 3);
            __builtin_amdgcn_global_load_lds(
                (const __attribute__((address_space(1))) void*)src,
                (__attribute__((address_space(3))) void*)&Kl[b][(w * 8 + 4 * i) * 128],
                16, 0, 0);
        }
        #pragma unroll
        for (int i = 0; i < 2; ++i) {
            int d = w * 16 + 8 * i + (l >> 3);
            const unsigned short* src = Vt + (size_t)(kvh * HD + d) * SEQ + kbase
                                           + (((l & 7) ^ (d & 7)) << 3);
            __builtin_amdgcn_global_load_lds(
                (const __attribute__((address_space(1))) void*)src,
                (__attribute__((address_space(3))) void*)&Vl[b][(w * 16 + 8 * i) * 64],
                16, 0, 0);
        }
    };

    STAGE(0, 0);
    __syncthreads();
    int cur = 0;

    for (int kt = 0; kt < nt; ++kt) {
        const int kbase = kt * 64;
        if (kt + 1 < nt) STAGE(kt + 1, cur ^ 1);

        if (kbase <= qw + 15) {
            // ---- QK^T: 16q x 64k ----
            f32x4 sc[4] = {};
            #pragma unroll
            for (int c = 0; c < 4; ++c) {
                int key = c * 16 + lr;
                #pragma unroll
                for (int f = 0; f < 4; ++f) {
                    bf16x8 kb = *reinterpret_cast<const bf16x8*>(
                        &Kl[cur][(key * 128 + f * 32 + lg * 8) ^ ((key & 7) << 3)]);
                    sc[c] = __builtin_amdgcn_mfma_f32_16x16x32_bf16(qf[f], kb, sc[c], 0, 0, 0);
                }
            }

            // ---- fixed-max softmax: p = exp(s*scale - 8), no cross-lane ----
            const bool diag = (kbase + 63 > qw);
            #pragma unroll
            for (int j = 0; j < 4; ++j) {
                int q = qw + lg * 4 + j;
                int prow = lg * 4 + j;
                float ps = 0.f;
                #pragma unroll
                for (int c = 0; c < 4; ++c) {
                    float p = __expf(sc[c][j] * scale - 8.0f);
                    if (diag && (kbase + c * 16 + lr > q)) p = 0.f;
                    ps += p;
                    Pl[w][(prow * 64 + c * 16 + lr) ^ ((prow & 7) << 3)] = f2bf(p);
                }
                lsum[j] += ps;
            }

            // ---- PV ----
            bf16x8 pa0 = *reinterpret_cast<const bf16x8*>(
                &Pl[w][(lr * 64 + lg * 8) ^ ((lr & 7) << 3)]);
            bf16x8 pa1 = *reinterpret_cast<const bf16x8*>(
                &Pl[w][(lr * 64 + 32 + lg * 8) ^ ((lr & 7) << 3)]);
            #pragma unroll
            for (int o = 0; o < 8; ++o) {
                int d = o * 16 + lr;
                bf16x8 bv0 = *reinterpret_cast<const bf16x8*>(
                    &Vl[cur][(d * 64 + lg * 8) ^ ((d & 7) << 3)]);
                bf16x8 bv1 = *reinterpret_cast<const bf16x8*>(
                    &Vl[cur][(d * 64 + 32 + lg * 8) ^ ((d & 7) << 3)]);
                po[o] = __builtin_amdgcn_mfma_f32_16x16x32_bf16(pa0, bv0, po[o], 0, 0, 0);
                po[o] = __builtin_amdgcn_mfma_f32_16x16x32_bf16(pa1, bv1, po[o], 0, 0, 0);
            }
        }
        __syncthreads();     // waves done with buf[cur]; buf[cur^1] loads drained
        cur ^= 1;
    }

    // ---- epilogue: one deferred row-sum reduce, then normalize ----
    #pragma unroll
    for (int j = 0; j < 4; ++j) {
        float s = lsum[j];
        s += __shfl_xor(s, 1);
        s += __shfl_xor(s, 2);
        s += __shfl_xor(s, 4);
        s += __shfl_xor(s, 8);
        float inv = 1.f / s;
        int q = qw + lg * 4 + j;
        #pragma unroll
        for (int o = 0; o < 8; ++o)
            Ob[(size_t)q * DIM + h * HD + o * 16 + lr] = f2bf(po[o][j] * inv);
    }
}

// ---------------------------------------------------------------------------
extern "C" void kernel_launch(void* const* d_in, const int* in_sizes, int n_in,
                              void* d_out, int out_size, void* d_ws, size_t ws_size,
                              hipStream_t stream) {
    const float* x    = (const float*)d_in[0];
    const float* wq   = (const float*)d_in[1];
    const float* wk   = (const float*)d_in[2];
    const float* wv   = (const float*)d_in[3];
    const float* wo   = (const float*)d_in[4];
    const float* cosT = (const float*)d_in[5];
    const float* sinT = (const float*)d_in[6];
    float* out = (float*)d_out;

    unsigned short* ws = (unsigned short*)d_ws;
    const bool big = ws_size >= (size_t)136 * 1024 * 1024;

    if (big) {
        unsigned short* xb   = ws;                                   // 2048x4096
        unsigned short* wqkv = xb   + (size_t)SEQ * DIM;             // 6144x4096 (wq|wk|wv)
        unsigned short* wob  = wqkv + (size_t)(DIM + 2 * KVDIM) * DIM; // 4096x4096
        unsigned short* Qb   = wob  + (size_t)DIM * DIM;             // 2048x4096
        unsigned short* Kb   = Qb   + (size_t)SEQ * DIM;             // 2048x1024
        unsigned short* Vtb  = Kb   + (size_t)SEQ * KVDIM;           // 1024x2048 (transposed)
        unsigned short* Ob   = Vtb  + (size_t)KVDIM * SEQ;           // 2048x4096

        cvt5_kernel<<<2048, 256, 0, stream>>>(x, wq, wk, wv, wo, ws);

        gemm_bt<true, true, 5><<<dim3(48, 16), 256, 0, stream>>>(
            xb, wqkv, Qb, Kb, Vtb, 0, cosT, sinT);
        attn_kernel<<<dim3(16, 32), 512, 0, stream>>>(Qb, Kb, Vtb, Ob);
        gemm_bt<true, true, 3><<<dim3(32, 16), 256, 0, stream>>>(
            Ob, wob, out, nullptr, nullptr, DIM, nullptr, nullptr);
    } else {
        unsigned short* Qb  = ws;
        unsigned short* Kb  = Qb  + (size_t)SEQ * DIM;
        unsigned short* Vtb = Kb  + (size_t)SEQ * KVDIM;
        unsigned short* Ob  = Vtb + (size_t)KVDIM * SEQ;

        gemm_bt<false, false, 1><<<dim3(32, 16), 256, 0, stream>>>(
            x, wq, Qb, nullptr, nullptr, DIM, cosT, sinT);
        gemm_bt<false, false, 1><<<dim3(8, 16),  256, 0, stream>>>(
            x, wk, Kb, nullptr, nullptr, KVDIM, cosT, sinT);
        gemm_bt<false, false, 2><<<dim3(8, 16),  256, 0, stream>>>(
            x, wv, Vtb, nullptr, nullptr, 0, nullptr, nullptr);
        attn_kernel<<<dim3(16, 32), 512, 0, stream>>>(Qb, Kb, Vtb, Ob);
        gemm_bt<true, false, 3><<<dim3(32, 16), 256, 0, stream>>>(
            Ob, wo, out, nullptr, nullptr, DIM, nullptr, nullptr);
    }
}